// Round 9
// baseline (436.012 us; speedup 1.0000x reference)
//
#include <hip/hip_runtime.h>
#include <hip/hip_bf16.h>
#include <hip/hip_fp16.h>

#define D_MODEL 1024
#define D_STATE 16
#define D_CONV  4
#define D_INNER 2048
#define DT_RANK 64
#define B_SZ 2
#define SEQ 1024
#define MR (B_SZ*SEQ)   // 2048 rows total

#define BM 128
#define BN 128
#define BK 64
#define LDK (BK + 8)   // LDS row pitch: +8 bf16 -> 16B-aligned rows

typedef float floatx4 __attribute__((ext_vector_type(4)));
typedef short short8 __attribute__((ext_vector_type(8)));
typedef _Float16 half8 __attribute__((ext_vector_type(8)));

__device__ __forceinline__ float ldf(const __hip_bfloat16* p) { return __bfloat162float(*p); }
__device__ __forceinline__ float ldf(const float* p) { return *p; }
__device__ __forceinline__ short f2bf(float f) {
  __hip_bfloat16 h = __float2bfloat16(f);
  return *reinterpret_cast<short*>(&h);
}

// ---------- prep: fp32 -> bf16 cast ----------
__global__ __launch_bounds__(256) void cast_kernel(
    const float* __restrict__ in, __hip_bfloat16* __restrict__ out, int n)
{
  int i = blockIdx.x * 256 + threadIdx.x;
  if (i < n) out[i] = __float2bfloat16(in[i]);
}

// ---------- prep: fp32 [R][C] -> bf16 [C][R] transpose ----------
__global__ __launch_bounds__(256) void transpose_cast_kernel(
    const float* __restrict__ in, __hip_bfloat16* __restrict__ out, int R, int C)
{
  __shared__ float t[32][33];
  const int x = threadIdx.x & 31;
  const int y4 = (threadIdx.x >> 5) * 4;
  const int bx = blockIdx.x * 32;   // along C
  const int by = blockIdx.y * 32;   // along R
#pragma unroll
  for (int i = 0; i < 4; ++i)
    t[y4 + i][x] = in[(size_t)(by + y4 + i) * C + bx + x];
  __syncthreads();
#pragma unroll
  for (int i = 0; i < 4; ++i)
    out[(size_t)(bx + y4 + i) * R + by + x] = __float2bfloat16(t[x][y4 + i]);
}

// ---------- MFMA GEMM: C[M,N] = A[M,K] * Bt[N,K]^T ----------
// EPI 0: f32 store; 2: bf16 store; 3: f32 atomicAdd;
// 4: bf16 split store (col<D_INNER -> C, else -> C2);
// 5: fp16 TRANSPOSED softplus store + u-product:
//    deltaT(C)[col][row] = sp = softplus(acc + bias[col]);
//    uT(C2)[col][row]    = sp * Xc[row][col]  (Xc = xcb, bf16 row-major)
template <int EPI>
__global__ __launch_bounds__(256) void mfma_gemm(
    const __hip_bfloat16* __restrict__ A, int lda,
    const __hip_bfloat16* __restrict__ Bt, int ldb,
    const float* __restrict__ bias,
    void* __restrict__ C, void* __restrict__ C2,
    const __hip_bfloat16* __restrict__ Xc, int ldc,
    int M, int N, int Kc)
{
  __shared__ __hip_bfloat16 sA[BM][LDK];
  __shared__ __hip_bfloat16 sB[BN][LDK];
  const int tid = threadIdx.x;
  const int lane = tid & 63;
  const int wave = tid >> 6;
  const int wm = (wave & 1) * 64;
  const int wn = (wave >> 1) * 64;
  const int tm = lane & 15;
  const int quad = lane >> 4;
  const int m0 = blockIdx.y * BM;
  const int n0 = blockIdx.x * BN;
  const int kbeg = blockIdx.z * Kc;

  floatx4 acc[4][4];
#pragma unroll
  for (int i = 0; i < 4; ++i)
#pragma unroll
    for (int j = 0; j < 4; ++j) acc[i][j] = (floatx4){0.f, 0.f, 0.f, 0.f};

  for (int k0 = kbeg; k0 < kbeg + Kc; k0 += BK) {
#pragma unroll
    for (int i = 0; i < 4; ++i) {
      int q = tid + 256 * i;          // 0..1023
      int r = q >> 3;                 // 0..127
      int c = (q & 7) * 8;            // 0..56
      *(short8*)&sA[r][c] =
          *(const short8*)&A[(size_t)(m0 + r) * lda + k0 + c];
      int nr = n0 + r;
      if (nr < N) {
        *(short8*)&sB[r][c] =
            *(const short8*)&Bt[(size_t)nr * ldb + k0 + c];
      } else {
        *(short8*)&sB[r][c] = (short8){0,0,0,0,0,0,0,0};
      }
    }
    __syncthreads();
#pragma unroll
    for (int kk = 0; kk < BK; kk += 32) {
      short8 af[4], bfr[4];
#pragma unroll
      for (int i = 0; i < 4; ++i)
        af[i] = *(const short8*)&sA[wm + i * 16 + tm][kk + quad * 8];
#pragma unroll
      for (int j = 0; j < 4; ++j)
        bfr[j] = *(const short8*)&sB[wn + j * 16 + tm][kk + quad * 8];
#pragma unroll
      for (int i = 0; i < 4; ++i)
#pragma unroll
        for (int j = 0; j < 4; ++j)
          acc[i][j] = __builtin_amdgcn_mfma_f32_16x16x32_bf16(
              af[i], bfr[j], acc[i][j], 0, 0, 0);
    }
    __syncthreads();
  }

  // epilogue: C/D layout col=lane&15, row=quad*4+reg
#pragma unroll
  for (int i = 0; i < 4; ++i) {
#pragma unroll
    for (int j = 0; j < 4; ++j) {
      int col = n0 + wn + j * 16 + tm;
      if (col >= N) continue;
      int row = m0 + wm + i * 16 + quad * 4;
#pragma unroll
      for (int r = 0; r < 4; ++r) {
        float v = acc[i][j][r];
        size_t off = (size_t)(row + r) * ldc + col;
        if (EPI == 0) {
          ((float*)C)[off] = v;
        } else if (EPI == 2) {
          ((__hip_bfloat16*)C)[off] = __float2bfloat16(v);
        } else if (EPI == 3) {
          atomicAdd(&((float*)C)[off], v);
        } else if (EPI == 4) {
          if (col < D_INNER)
            ((__hip_bfloat16*)C)[(size_t)(row + r) * D_INNER + col] = __float2bfloat16(v);
          else
            ((__hip_bfloat16*)C2)[(size_t)(row + r) * D_INNER + (col - D_INNER)] = __float2bfloat16(v);
        } else {  // EPI 5: transposed fp16 softplus + u = sp*xc
          float xv = v + bias[col];
          float sp = (xv > 15.f) ? xv : log1pf(__expf(xv));
          size_t toff = (size_t)col * MR + (row + r);
          ((__half*)C)[toff] = __float2half(sp);
          float xc = ldf(&Xc[(size_t)(row + r) * D_INNER + col]);
          ((__half*)C2)[toff] = __float2half(sp * xc);
        }
      }
    }
  }
}

// ---------- depthwise causal conv (4 taps) + bias + SiLU (row-major out) ----------
__global__ __launch_bounds__(256) void conv_silu_kernel(
    const __hip_bfloat16* __restrict__ xe,    // [MR, D_INNER]
    const float* __restrict__ cw,
    const float* __restrict__ cb,
    __hip_bfloat16* __restrict__ xcb)         // [MR, D_INNER]
{
  int idx = blockIdx.x * 256 + threadIdx.x;     // over MR*D_INNER
  int c = idx & (D_INNER - 1);
  int row = idx >> 11;                          // b*SEQ + l
  int l = row & (SEQ - 1);
  float acc = cb[c];
  const __hip_bfloat16* p = &xe[(size_t)row * D_INNER + c];
  acc += ldf(p) * cw[c * D_CONV + 3];
  if (l >= 1) acc += ldf(p - D_INNER) * cw[c * D_CONV + 2];
  if (l >= 2) acc += ldf(p - 2 * D_INNER) * cw[c * D_CONV + 1];
  if (l >= 3) acc += ldf(p - 3 * D_INNER) * cw[c * D_CONV + 0];
  xcb[idx] = __float2bfloat16(acc / (1.f + __expf(-acc)));   // silu
}

// ---------- chunked parallel SSM scan, d-major vectorized streams ----------
// One block (512 thr) per (b,d) chain; thread = (n = tid&15, seg = tid>>4, 32 segs x 32 steps).
// Reads deltaT/uT fp16 (contiguous along l), B/C from xdbl fp32 (L2-resident).
// Writes yT[d][row] = sum_n h*C  (pre-gate, pre-D-skip).
__global__ __launch_bounds__(512) void scan_kernel(
    const __half* __restrict__ deltaT,          // [D_INNER, MR]
    const __half* __restrict__ uT,              // [D_INNER, MR]  u = delta*xc
    const float* __restrict__ xdbl,             // [MR, 96]  (B at +64, C at +80)
    const float* __restrict__ A_log,            // [2048,16]
    __hip_bfloat16* __restrict__ yT)            // [D_INNER, MR]
{
  __shared__ float s_ap[32][16];   // [seg][n]
  __shared__ float s_bc[32][16];
  __shared__ float s_h0[32][16];
  const int tid = threadIdx.x;
  const int n = tid & 15;
  const int seg = tid >> 4;                  // 0..31
  const int chain = blockIdx.x;              // 0..4095
  const int b = chain >> 11;
  const int d = chain & (D_INNER - 1);
  const float a_c = -__expf(A_log[d * D_STATE + n]);
  const int rbase = b * SEQ + seg * 32;            // row index base
  const size_t cbase = (size_t)d * MR + rbase;     // d-major base (16B aligned)

  // Pass 1: per-segment affine composition (16B loads, 8 steps each).
  float aprod = 1.f, bacc = 0.f;
  for (int c8 = 0; c8 < 4; ++c8) {
    half8 dv8 = *(const half8*)&deltaT[cbase + c8 * 8];
    half8 u8  = *(const half8*)&uT[cbase + c8 * 8];
#pragma unroll
    for (int j = 0; j < 8; ++j) {
      float dv = (float)dv8[j];
      float uu = (float)u8[j];
      float Bv = xdbl[(size_t)(rbase + c8 * 8 + j) * 96 + DT_RANK + n];
      float a  = __expf(dv * a_c);
      aprod *= a;
      bacc = a * bacc + uu * Bv;
    }
  }
  s_ap[seg][n] = aprod;
  s_bc[seg][n] = bacc;
  __syncthreads();

  // Inter-segment exclusive scan (16 threads, one per n; 32 serial steps).
  if (tid < 16) {
    float h = 0.f;
#pragma unroll
    for (int s = 0; s < 32; ++s) {
      s_h0[s][tid] = h;
      h = s_ap[s][tid] * h + s_bc[s][tid];
    }
  }
  __syncthreads();

  // Pass 2: rescan with entry state; reduce over n; buffered 16B stores.
  float h = s_h0[seg][n];
  for (int c8 = 0; c8 < 4; ++c8) {
    half8 dv8 = *(const half8*)&deltaT[cbase + c8 * 8];
    half8 u8  = *(const half8*)&uT[cbase + c8 * 8];
    short8 ybuf;
#pragma unroll
    for (int j = 0; j < 8; ++j) {
      float dv = (float)dv8[j];
      float uu = (float)u8[j];
      size_t rr = (size_t)(rbase + c8 * 8 + j) * 96;
      float Bv = xdbl[rr + DT_RANK + n];
      float Cv = xdbl[rr + DT_RANK + D_STATE + n];
      float a  = __expf(dv * a_c);
      h = a * h + uu * Bv;
      float contrib = h * Cv;
#pragma unroll
      for (int off = 8; off; off >>= 1) contrib += __shfl_xor(contrib, off, 16);
      ybuf[j] = f2bf(contrib);
    }
    if (n == 0)
      *(short8*)&yT[cbase + c8 * 8] = ybuf;
  }
}

// ---------- gate: ygb[row][d] = (yT[d][row] + xc*D) * silu(z[row][d]) ----------
__global__ __launch_bounds__(256) void gate_kernel(
    const __hip_bfloat16* __restrict__ yT,   // [D_INNER, MR]
    const __hip_bfloat16* __restrict__ z,    // [MR, D_INNER]
    const __hip_bfloat16* __restrict__ xcb,  // [MR, D_INNER]
    const float* __restrict__ Dp,            // [2048]
    __hip_bfloat16* __restrict__ ygb)        // [MR, D_INNER]
{
  __shared__ float t[32][33];
  const int x = threadIdx.x & 31;
  const int y4 = (threadIdx.x >> 5) * 4;
  const int bx = blockIdx.x * 32;   // along MR
  const int by = blockIdx.y * 32;   // along D_INNER
#pragma unroll
  for (int i = 0; i < 4; ++i)
    t[y4 + i][x] = ldf(&yT[(size_t)(by + y4 + i) * MR + bx + x]);
  __syncthreads();
#pragma unroll
  for (int i = 0; i < 4; ++i) {
    int row = bx + y4 + i;
    int d = by + x;
    float zv = ldf(&z[(size_t)row * D_INNER + d]);
    float xc = ldf(&xcb[(size_t)row * D_INNER + d]);
    float yv = t[x][y4 + i] + xc * Dp[d];
    ygb[(size_t)row * D_INNER + d] = __float2bfloat16(yv * (zv / (1.f + __expf(-zv))));
  }
}

extern "C" void kernel_launch(void* const* d_in, const int* in_sizes, int n_in,
                              void* d_out, int out_size, void* d_ws, size_t ws_size,
                              hipStream_t stream)
{
  const float* x     = (const float*)d_in[0];
  const float* W_in  = (const float*)d_in[1];
  const float* cw    = (const float*)d_in[2];
  const float* cb    = (const float*)d_in[3];
  const float* W_x   = (const float*)d_in[4];
  const float* W_dt  = (const float*)d_in[5];
  const float* b_dt  = (const float*)d_in[6];
  const float* A_log = (const float*)d_in[7];
  const float* Dp    = (const float*)d_in[8];
  const float* W_out = (const float*)d_in[9];
  float* out = (float*)d_out;

  // Workspace: 45.125 MiB. Lifetime overlays (stream-ordered):
  //   [ 0, 8)  WinT (prep->G1) -> uT fp16 (G4->scan) -> ygb (gate->G6)
  //   [ 8,16)  xb[8,12) WxT[12,12.375) WdtT[12.375,12.625) -> yT (scan->gate)
  //   [16,24)  xe  (G1->conv) -> deltaT fp16 (G4->scan)
  //   [24,32)  z   (G1->gate)
  //   [32,40)  xcb (conv->gate)
  //   [40,40.75)   xdbl f32 (G3->scan)
  //   [40.75,41.125) xdblb (cast->G4)
  //   [41.125,45.125) WoutT (prep->G6)
  const size_t MiB = 1 << 20;
  char* wsb = (char*)d_ws;
  __hip_bfloat16* WinT   = (__hip_bfloat16*)(wsb);
  __half*         uT     = (__half*)(wsb);
  __hip_bfloat16* ygb    = (__hip_bfloat16*)(wsb);
  __hip_bfloat16* xb     = (__hip_bfloat16*)(wsb + 8 * MiB);
  __hip_bfloat16* WxT    = (__hip_bfloat16*)(wsb + 12 * MiB);
  __hip_bfloat16* WdtT   = (__hip_bfloat16*)(wsb + 12 * MiB + 384 * 1024);
  __hip_bfloat16* yT     = (__hip_bfloat16*)(wsb + 8 * MiB);
  __hip_bfloat16* xe     = (__hip_bfloat16*)(wsb + 16 * MiB);
  __half*         deltaT = (__half*)(wsb + 16 * MiB);
  __hip_bfloat16* z      = (__hip_bfloat16*)(wsb + 24 * MiB);
  __hip_bfloat16* xcb    = (__hip_bfloat16*)(wsb + 32 * MiB);
  float*          xdbl   = (float*)(wsb + 40 * MiB);
  __hip_bfloat16* xdblb  = (__hip_bfloat16*)(wsb + 40 * MiB + 768 * 1024);
  __hip_bfloat16* WoutT  = (__hip_bfloat16*)(wsb + 41 * MiB + 128 * 1024);

  dim3 blk(256);

  // prep: casts + transposes (bf16, B^T K-contiguous layouts)
  cast_kernel<<<(MR * D_MODEL) / 256, blk, 0, stream>>>(x, xb, MR * D_MODEL);
  transpose_cast_kernel<<<dim3(4096 / 32, 1024 / 32), blk, 0, stream>>>(W_in, WinT, D_MODEL, 2 * D_INNER);
  transpose_cast_kernel<<<dim3(96 / 32, 2048 / 32), blk, 0, stream>>>(W_x, WxT, D_INNER, 96);
  transpose_cast_kernel<<<dim3(2048 / 32, 64 / 32), blk, 0, stream>>>(W_dt, WdtT, DT_RANK, D_INNER);
  transpose_cast_kernel<<<dim3(1024 / 32, 2048 / 32), blk, 0, stream>>>(W_out, WoutT, D_INNER, D_MODEL);

  // 1. [xe|z] = x @ W_in   (M=2048, N=4096, K=1024), bf16 split store
  mfma_gemm<4><<<dim3(4096 / BN, MR / BM, 1), blk, 0, stream>>>(
      xb, D_MODEL, WinT, D_MODEL, nullptr, xe, z, nullptr, D_INNER, MR, 2 * D_INNER, D_MODEL);

  // 2. conv + silu -> xcb (row-major)
  conv_silu_kernel<<<(MR * D_INNER) / 256, blk, 0, stream>>>(xe, cw, cb, xcb);

  // 3. xdbl = xc @ W_x   (M=2048, N=96, K=2048), split-K=8 atomics
  hipMemsetAsync(xdbl, 0, (size_t)MR * 96 * 4, stream);
  mfma_gemm<3><<<dim3(1, MR / BM, 8), blk, 0, stream>>>(
      xcb, D_INNER, WxT, D_INNER, nullptr, xdbl, nullptr, nullptr, 96, MR, 96, D_INNER / 8);
  cast_kernel<<<(MR * 96) / 256, blk, 0, stream>>>(xdbl, xdblb, MR * 96);

  // 4. deltaT = softplus(...)^T fp16; uT = deltaT * xc (fused epilogue)
  mfma_gemm<5><<<dim3(D_INNER / BN, MR / BM, 1), blk, 0, stream>>>(
      xdblb, 96, WdtT, DT_RANK, b_dt, deltaT, uT, xcb, 0, MR, D_INNER, DT_RANK);

  // 5. chunked parallel SSM scan (d-major, 512 thr, 32 segs) -> yT
  scan_kernel<<<B_SZ * D_INNER, dim3(512), 0, stream>>>(deltaT, uT, xdbl, A_log, yT);

  // 5b. gate: ygb = (yT^T + xc*D) * silu(z)
  gate_kernel<<<dim3(MR / 32, D_INNER / 32), blk, 0, stream>>>(yT, z, xcb, Dp, ygb);

  // 6. out = yg @ W_out   (M=2048, N=1024, K=2048), split-K=2 atomics, fp32
  hipMemsetAsync(out, 0, (size_t)MR * D_MODEL * 4, stream);
  mfma_gemm<3><<<dim3(D_MODEL / BN, MR / BM, 2), blk, 0, stream>>>(
      ygb, D_INNER, WoutT, D_INNER, nullptr, out, nullptr, nullptr, D_MODEL, MR, D_MODEL, D_INNER / 2);
}

// Round 10
// 364.868 us; speedup vs baseline: 1.1950x; 1.1950x over previous
//
#include <hip/hip_runtime.h>
#include <hip/hip_bf16.h>
#include <hip/hip_fp16.h>

#define D_MODEL 1024
#define D_STATE 16
#define D_CONV  4
#define D_INNER 2048
#define DT_RANK 64
#define B_SZ 2
#define SEQ 1024
#define MR (B_SZ*SEQ)   // 2048 rows total

#define BM 128
#define BN 128
#define BK 64
#define LDK (BK + 8)   // LDS row pitch: +8 bf16 -> 16B-aligned rows
#define TP (BM + 4)    // fp16 transpose-staging pitch: +4 halfs -> conflict-free

typedef float floatx4 __attribute__((ext_vector_type(4)));
typedef short short8 __attribute__((ext_vector_type(8)));
typedef _Float16 half8 __attribute__((ext_vector_type(8)));

__device__ __forceinline__ float ldf(const __hip_bfloat16* p) { return __bfloat162float(*p); }
__device__ __forceinline__ float ldf(const float* p) { return *p; }
__device__ __forceinline__ short f2bf(float f) {
  __hip_bfloat16 h = __float2bfloat16(f);
  return *reinterpret_cast<short*>(&h);
}

// ---------- prep: fp32 -> bf16 cast ----------
__global__ __launch_bounds__(256) void cast_kernel(
    const float* __restrict__ in, __hip_bfloat16* __restrict__ out, int n)
{
  int i = blockIdx.x * 256 + threadIdx.x;
  if (i < n) out[i] = __float2bfloat16(in[i]);
}

// ---------- prep: fp32 [R][C] -> bf16 [C][R] transpose ----------
__global__ __launch_bounds__(256) void transpose_cast_kernel(
    const float* __restrict__ in, __hip_bfloat16* __restrict__ out, int R, int C)
{
  __shared__ float t[32][33];
  const int x = threadIdx.x & 31;
  const int y4 = (threadIdx.x >> 5) * 4;
  const int bx = blockIdx.x * 32;   // along C
  const int by = blockIdx.y * 32;   // along R
#pragma unroll
  for (int i = 0; i < 4; ++i)
    t[y4 + i][x] = in[(size_t)(by + y4 + i) * C + bx + x];
  __syncthreads();
#pragma unroll
  for (int i = 0; i < 4; ++i)
    out[(size_t)(bx + y4 + i) * R + by + x] = __float2bfloat16(t[x][y4 + i]);
}

// ---------- MFMA GEMM: C[M,N] = A[M,K] * Bt[N,K]^T ----------
// EPI 0: f32 store; 2: bf16 store; 3: f32 atomicAdd;
// 4: bf16 split store (col<D_INNER -> C, else -> C2);
// 5: fp16 TRANSPOSED softplus + u-product via LDS staging (coalesced):
//    deltaT(C)[col][row] = sp = softplus(acc + bias[col]);
//    uT(C2)[col][row]    = sp * Xc[row][col]
template <int EPI>
__global__ __launch_bounds__(256) void mfma_gemm(
    const __hip_bfloat16* __restrict__ A, int lda,
    const __hip_bfloat16* __restrict__ Bt, int ldb,
    const float* __restrict__ bias,
    void* __restrict__ C, void* __restrict__ C2,
    const __hip_bfloat16* __restrict__ Xc, int ldc,
    int M, int N, int Kc)
{
  __shared__ __hip_bfloat16 sA[BM][LDK];
  __shared__ __hip_bfloat16 sB[BN][LDK];
  const int tid = threadIdx.x;
  const int lane = tid & 63;
  const int wave = tid >> 6;
  const int wm = (wave & 1) * 64;
  const int wn = (wave >> 1) * 64;
  const int tm = lane & 15;
  const int quad = lane >> 4;
  const int m0 = blockIdx.y * BM;
  const int n0 = blockIdx.x * BN;
  const int kbeg = blockIdx.z * Kc;

  floatx4 acc[4][4];
#pragma unroll
  for (int i = 0; i < 4; ++i)
#pragma unroll
    for (int j = 0; j < 4; ++j) acc[i][j] = (floatx4){0.f, 0.f, 0.f, 0.f};

  for (int k0 = kbeg; k0 < kbeg + Kc; k0 += BK) {
#pragma unroll
    for (int i = 0; i < 4; ++i) {
      int q = tid + 256 * i;          // 0..1023
      int r = q >> 3;                 // 0..127
      int c = (q & 7) * 8;            // 0..56
      *(short8*)&sA[r][c] =
          *(const short8*)&A[(size_t)(m0 + r) * lda + k0 + c];
      int nr = n0 + r;
      if (nr < N) {
        *(short8*)&sB[r][c] =
            *(const short8*)&Bt[(size_t)nr * ldb + k0 + c];
      } else {
        *(short8*)&sB[r][c] = (short8){0,0,0,0,0,0,0,0};
      }
    }
    __syncthreads();
#pragma unroll
    for (int kk = 0; kk < BK; kk += 32) {
      short8 af[4], bfr[4];
#pragma unroll
      for (int i = 0; i < 4; ++i)
        af[i] = *(const short8*)&sA[wm + i * 16 + tm][kk + quad * 8];
#pragma unroll
      for (int j = 0; j < 4; ++j)
        bfr[j] = *(const short8*)&sB[wn + j * 16 + tm][kk + quad * 8];
#pragma unroll
      for (int i = 0; i < 4; ++i)
#pragma unroll
        for (int j = 0; j < 4; ++j)
          acc[i][j] = __builtin_amdgcn_mfma_f32_16x16x32_bf16(
              af[i], bfr[j], acc[i][j], 0, 0, 0);
    }
    __syncthreads();
  }

  if (EPI == 5) {
    // Transposed dual store via LDS (sA/sB dead; reuse as fp16 staging).
    // Slice j: 32 cols (16 per wn-group) x 128 rows, stored d-major coalesced.
    __half (*tD)[TP] = reinterpret_cast<__half(*)[TP]>(&sA[0][0]);  // [32][TP]
    __half (*tU)[TP] = reinterpret_cast<__half(*)[TP]>(&sB[0][0]);
    const int lc = (wave >> 1) * 16 + tm;
#pragma unroll
    for (int j = 0; j < 4; ++j) {
      const int col = n0 + wn + j * 16 + tm;
      const float bv = bias[col];
#pragma unroll
      for (int i = 0; i < 4; ++i) {
        const int lr = wm + i * 16 + quad * 4;
#pragma unroll
        for (int r = 0; r < 4; ++r) {
          float xv = acc[i][j][r] + bv;
          float sp = (xv > 15.f) ? xv : log1pf(__expf(xv));
          float xc = ldf(&Xc[(size_t)(m0 + lr + r) * D_INNER + col]);
          tD[lc][lr + r] = __float2half(sp);
          tU[lc][lr + r] = __float2half(sp * xc);
        }
      }
      __syncthreads();
      const int c = tid >> 3;          // 0..31 (LDS col)
      const int seg = tid & 7;         // 8 segments x 16 rows
      const int gcol = n0 + (c >> 4) * 64 + j * 16 + (c & 15);
      const size_t goff = (size_t)gcol * MR + m0 + seg * 16;
      *(half8*)&((__half*)C)[goff]      = *(const half8*)&tD[c][seg * 16];
      *(half8*)&((__half*)C)[goff + 8]  = *(const half8*)&tD[c][seg * 16 + 8];
      *(half8*)&((__half*)C2)[goff]     = *(const half8*)&tU[c][seg * 16];
      *(half8*)&((__half*)C2)[goff + 8] = *(const half8*)&tU[c][seg * 16 + 8];
      __syncthreads();
    }
    return;
  }

  // epilogue: C/D layout col=lane&15, row=quad*4+reg
#pragma unroll
  for (int i = 0; i < 4; ++i) {
#pragma unroll
    for (int j = 0; j < 4; ++j) {
      int col = n0 + wn + j * 16 + tm;
      if (col >= N) continue;
      int row = m0 + wm + i * 16 + quad * 4;
#pragma unroll
      for (int r = 0; r < 4; ++r) {
        float v = acc[i][j][r];
        size_t off = (size_t)(row + r) * ldc + col;
        if (EPI == 0) {
          ((float*)C)[off] = v;
        } else if (EPI == 2) {
          ((__hip_bfloat16*)C)[off] = __float2bfloat16(v);
        } else if (EPI == 3) {
          atomicAdd(&((float*)C)[off], v);
        } else if (EPI == 4) {
          if (col < D_INNER)
            ((__hip_bfloat16*)C)[(size_t)(row + r) * D_INNER + col] = __float2bfloat16(v);
          else
            ((__hip_bfloat16*)C2)[(size_t)(row + r) * D_INNER + (col - D_INNER)] = __float2bfloat16(v);
        }
      }
    }
  }
}

// ---------- depthwise causal conv (4 taps) + bias + SiLU (row-major out) ----------
__global__ __launch_bounds__(256) void conv_silu_kernel(
    const __hip_bfloat16* __restrict__ xe,    // [MR, D_INNER]
    const float* __restrict__ cw,
    const float* __restrict__ cb,
    __hip_bfloat16* __restrict__ xcb)         // [MR, D_INNER]
{
  int idx = blockIdx.x * 256 + threadIdx.x;     // over MR*D_INNER
  int c = idx & (D_INNER - 1);
  int row = idx >> 11;                          // b*SEQ + l
  int l = row & (SEQ - 1);
  float acc = cb[c];
  const __hip_bfloat16* p = &xe[(size_t)row * D_INNER + c];
  acc += ldf(p) * cw[c * D_CONV + 3];
  if (l >= 1) acc += ldf(p - D_INNER) * cw[c * D_CONV + 2];
  if (l >= 2) acc += ldf(p - 2 * D_INNER) * cw[c * D_CONV + 1];
  if (l >= 3) acc += ldf(p - 3 * D_INNER) * cw[c * D_CONV + 0];
  xcb[idx] = __float2bfloat16(acc / (1.f + __expf(-acc)));   // silu
}

// ---------- chunked parallel SSM scan, d-major vectorized streams ----------
// One block (512 thr) per (b,d) chain; thread = (n = tid&15, seg = tid>>4, 32 segs x 32 steps).
__global__ __launch_bounds__(512) void scan_kernel(
    const __half* __restrict__ deltaT,          // [D_INNER, MR]
    const __half* __restrict__ uT,              // [D_INNER, MR]  u = delta*xc
    const float* __restrict__ xdbl,             // [MR, 96]  (B at +64, C at +80)
    const float* __restrict__ A_log,            // [2048,16]
    __hip_bfloat16* __restrict__ yT)            // [D_INNER, MR]
{
  __shared__ float s_ap[32][16];   // [seg][n]
  __shared__ float s_bc[32][16];
  __shared__ float s_h0[32][16];
  const int tid = threadIdx.x;
  const int n = tid & 15;
  const int seg = tid >> 4;                  // 0..31
  const int chain = blockIdx.x;              // 0..4095
  const int b = chain >> 11;
  const int d = chain & (D_INNER - 1);
  const float a_c = -__expf(A_log[d * D_STATE + n]);
  const int rbase = b * SEQ + seg * 32;            // row index base
  const size_t cbase = (size_t)d * MR + rbase;     // d-major base (16B aligned)

  // Pass 1: per-segment affine composition (16B loads, 8 steps each).
  float aprod = 1.f, bacc = 0.f;
  for (int c8 = 0; c8 < 4; ++c8) {
    half8 dv8 = *(const half8*)&deltaT[cbase + c8 * 8];
    half8 u8  = *(const half8*)&uT[cbase + c8 * 8];
#pragma unroll
    for (int j = 0; j < 8; ++j) {
      float dv = (float)dv8[j];
      float uu = (float)u8[j];
      float Bv = xdbl[(size_t)(rbase + c8 * 8 + j) * 96 + DT_RANK + n];
      float a  = __expf(dv * a_c);
      aprod *= a;
      bacc = a * bacc + uu * Bv;
    }
  }
  s_ap[seg][n] = aprod;
  s_bc[seg][n] = bacc;
  __syncthreads();

  // Inter-segment exclusive scan (16 threads, one per n; 32 serial steps).
  if (tid < 16) {
    float h = 0.f;
#pragma unroll
    for (int s = 0; s < 32; ++s) {
      s_h0[s][tid] = h;
      h = s_ap[s][tid] * h + s_bc[s][tid];
    }
  }
  __syncthreads();

  // Pass 2: rescan with entry state; reduce over n; buffered 16B stores.
  float h = s_h0[seg][n];
  for (int c8 = 0; c8 < 4; ++c8) {
    half8 dv8 = *(const half8*)&deltaT[cbase + c8 * 8];
    half8 u8  = *(const half8*)&uT[cbase + c8 * 8];
    short8 ybuf;
#pragma unroll
    for (int j = 0; j < 8; ++j) {
      float dv = (float)dv8[j];
      float uu = (float)u8[j];
      size_t rr = (size_t)(rbase + c8 * 8 + j) * 96;
      float Bv = xdbl[rr + DT_RANK + n];
      float Cv = xdbl[rr + DT_RANK + D_STATE + n];
      float a  = __expf(dv * a_c);
      h = a * h + uu * Bv;
      float contrib = h * Cv;
#pragma unroll
      for (int off = 8; off; off >>= 1) contrib += __shfl_xor(contrib, off, 16);
      ybuf[j] = f2bf(contrib);
    }
    if (n == 0)
      *(short8*)&yT[cbase + c8 * 8] = ybuf;
  }
}

// ---------- gate: ygb[row][d] = (yT[d][row] + xc*D) * silu(z[row][d]) ----------
__global__ __launch_bounds__(256) void gate_kernel(
    const __hip_bfloat16* __restrict__ yT,   // [D_INNER, MR]
    const __hip_bfloat16* __restrict__ z,    // [MR, D_INNER]
    const __hip_bfloat16* __restrict__ xcb,  // [MR, D_INNER]
    const float* __restrict__ Dp,            // [2048]
    __hip_bfloat16* __restrict__ ygb)        // [MR, D_INNER]
{
  __shared__ float t[32][33];
  const int x = threadIdx.x & 31;
  const int y4 = (threadIdx.x >> 5) * 4;
  const int bx = blockIdx.x * 32;   // along MR
  const int by = blockIdx.y * 32;   // along D_INNER
#pragma unroll
  for (int i = 0; i < 4; ++i)
    t[y4 + i][x] = ldf(&yT[(size_t)(by + y4 + i) * MR + bx + x]);
  __syncthreads();
#pragma unroll
  for (int i = 0; i < 4; ++i) {
    int row = bx + y4 + i;
    int d = by + x;
    float zv = ldf(&z[(size_t)row * D_INNER + d]);
    float xc = ldf(&xcb[(size_t)row * D_INNER + d]);
    float yv = t[x][y4 + i] + xc * Dp[d];
    ygb[(size_t)row * D_INNER + d] = __float2bfloat16(yv * (zv / (1.f + __expf(-zv))));
  }
}

extern "C" void kernel_launch(void* const* d_in, const int* in_sizes, int n_in,
                              void* d_out, int out_size, void* d_ws, size_t ws_size,
                              hipStream_t stream)
{
  const float* x     = (const float*)d_in[0];
  const float* W_in  = (const float*)d_in[1];
  const float* cw    = (const float*)d_in[2];
  const float* cb    = (const float*)d_in[3];
  const float* W_x   = (const float*)d_in[4];
  const float* W_dt  = (const float*)d_in[5];
  const float* b_dt  = (const float*)d_in[6];
  const float* A_log = (const float*)d_in[7];
  const float* Dp    = (const float*)d_in[8];
  const float* W_out = (const float*)d_in[9];
  float* out = (float*)d_out;

  // Workspace: 45.125 MiB. Lifetime overlays (stream-ordered):
  //   [ 0, 8)  WinT (prep->G1) -> uT fp16 (G4->scan) -> ygb (gate->G6)
  //   [ 8,16)  xb[8,12) WxT[12,12.375) WdtT[12.375,12.625) -> yT (scan->gate)
  //   [16,24)  xe  (G1->conv) -> deltaT fp16 (G4->scan)
  //   [24,32)  z   (G1->gate)
  //   [32,40)  xcb (conv->gate)
  //   [40,40.75)   xdbl f32 (G3->scan)
  //   [40.75,41.125) xdblb (cast->G4)
  //   [41.125,45.125) WoutT (prep->G6)
  const size_t MiB = 1 << 20;
  char* wsb = (char*)d_ws;
  __hip_bfloat16* WinT   = (__hip_bfloat16*)(wsb);
  __half*         uT     = (__half*)(wsb);
  __hip_bfloat16* ygb    = (__hip_bfloat16*)(wsb);
  __hip_bfloat16* xb     = (__hip_bfloat16*)(wsb + 8 * MiB);
  __hip_bfloat16* WxT    = (__hip_bfloat16*)(wsb + 12 * MiB);
  __hip_bfloat16* WdtT   = (__hip_bfloat16*)(wsb + 12 * MiB + 384 * 1024);
  __hip_bfloat16* yT     = (__hip_bfloat16*)(wsb + 8 * MiB);
  __hip_bfloat16* xe     = (__hip_bfloat16*)(wsb + 16 * MiB);
  __half*         deltaT = (__half*)(wsb + 16 * MiB);
  __hip_bfloat16* z      = (__hip_bfloat16*)(wsb + 24 * MiB);
  __hip_bfloat16* xcb    = (__hip_bfloat16*)(wsb + 32 * MiB);
  float*          xdbl   = (float*)(wsb + 40 * MiB);
  __hip_bfloat16* xdblb  = (__hip_bfloat16*)(wsb + 40 * MiB + 768 * 1024);
  __hip_bfloat16* WoutT  = (__hip_bfloat16*)(wsb + 41 * MiB + 128 * 1024);

  dim3 blk(256);

  // prep: casts + transposes (bf16, B^T K-contiguous layouts)
  cast_kernel<<<(MR * D_MODEL) / 256, blk, 0, stream>>>(x, xb, MR * D_MODEL);
  transpose_cast_kernel<<<dim3(4096 / 32, 1024 / 32), blk, 0, stream>>>(W_in, WinT, D_MODEL, 2 * D_INNER);
  transpose_cast_kernel<<<dim3(96 / 32, 2048 / 32), blk, 0, stream>>>(W_x, WxT, D_INNER, 96);
  transpose_cast_kernel<<<dim3(2048 / 32, 64 / 32), blk, 0, stream>>>(W_dt, WdtT, DT_RANK, D_INNER);
  transpose_cast_kernel<<<dim3(1024 / 32, 2048 / 32), blk, 0, stream>>>(W_out, WoutT, D_INNER, D_MODEL);

  // 1. [xe|z] = x @ W_in   (M=2048, N=4096, K=1024), bf16 split store
  mfma_gemm<4><<<dim3(4096 / BN, MR / BM, 1), blk, 0, stream>>>(
      xb, D_MODEL, WinT, D_MODEL, nullptr, xe, z, nullptr, D_INNER, MR, 2 * D_INNER, D_MODEL);

  // 2. conv + silu -> xcb (row-major)
  conv_silu_kernel<<<(MR * D_INNER) / 256, blk, 0, stream>>>(xe, cw, cb, xcb);

  // 3. xdbl = xc @ W_x   (M=2048, N=96, K=2048), split-K=8 atomics
  hipMemsetAsync(xdbl, 0, (size_t)MR * 96 * 4, stream);
  mfma_gemm<3><<<dim3(1, MR / BM, 8), blk, 0, stream>>>(
      xcb, D_INNER, WxT, D_INNER, nullptr, xdbl, nullptr, nullptr, 96, MR, 96, D_INNER / 8);
  cast_kernel<<<(MR * 96) / 256, blk, 0, stream>>>(xdbl, xdblb, MR * 96);

  // 4. deltaT = softplus(...)^T fp16; uT = deltaT * xc (LDS-staged coalesced stores)
  mfma_gemm<5><<<dim3(D_INNER / BN, MR / BM, 1), blk, 0, stream>>>(
      xdblb, 96, WdtT, DT_RANK, b_dt, deltaT, uT, xcb, 0, MR, D_INNER, DT_RANK);

  // 5. chunked parallel SSM scan (d-major, 512 thr, 32 segs) -> yT
  scan_kernel<<<B_SZ * D_INNER, dim3(512), 0, stream>>>(deltaT, uT, xdbl, A_log, yT);

  // 5b. gate: ygb = (yT^T + xc*D) * silu(z)
  gate_kernel<<<dim3(MR / 32, D_INNER / 32), blk, 0, stream>>>(yT, z, xcb, Dp, ygb);

  // 6. out = yg @ W_out   (M=2048, N=1024, K=2048), split-K=2 atomics, fp32
  hipMemsetAsync(out, 0, (size_t)MR * D_MODEL * 4, stream);
  mfma_gemm<3><<<dim3(D_MODEL / BN, MR / BM, 2), blk, 0, stream>>>(
      ygb, D_INNER, WoutT, D_INNER, nullptr, out, nullptr, nullptr, D_MODEL, MR, D_MODEL, D_INNER / 2);
}